// Round 3
// baseline (478.881 us; speedup 1.0000x reference)
//
#include <hip/hip_runtime.h>
#include <hip/hip_bf16.h>
#include <math.h>

// AttentionWithBias: B=4, N=1024, d=1024, H=16, hd=64
// bf16 MFMA (16x16x32), fp32 accumulate, fp32 softmax+bias.

typedef __bf16 bf16;
typedef bf16 bf16x8 __attribute__((ext_vector_type(8)));
typedef bf16 bf16x4 __attribute__((ext_vector_type(4)));
typedef float floatx4 __attribute__((ext_vector_type(4)));

#define MFMA16(a, b, c) __builtin_amdgcn_mfma_f32_16x16x32_bf16((a), (b), (c), 0, 0, 0)

__device__ __forceinline__ void gload_lds16(const bf16* g, bf16* l) {
  __builtin_amdgcn_global_load_lds(
      (const __attribute__((address_space(1))) unsigned int*)g,
      (__attribute__((address_space(3))) unsigned int*)l, 16, 0, 0);
}

// ---------------------------------------------------------------- convert
__global__ __launch_bounds__(256) void cvt_kernel(
    const float* __restrict__ x, const float* __restrict__ wq,
    const float* __restrict__ wk, const float* __restrict__ wv,
    const float* __restrict__ wo, bf16* __restrict__ dst) {
  long e = ((long)blockIdx.x * 256 + threadIdx.x) * 4;
  const float* src;
  if (e < 4194304) {
    src = x + e;
  } else {
    long r = (e - 4194304) >> 20;
    long off = (e - 4194304) & 1048575;
    src = (r == 0 ? wq : r == 1 ? wk : r == 2 ? wv : wo) + off;
  }
  float4 v = *reinterpret_cast<const float4*>(src);
  bf16x4 o = { (bf16)v.x, (bf16)v.y, (bf16)v.z, (bf16)v.w };
  *reinterpret_cast<bf16x4*>(dst + e) = o;
}

// ---------------------------------------------------------------- GEMM core
__device__ __forceinline__ void gemm_mainloop(const bf16* __restrict__ Ag,
                                              const bf16* __restrict__ Bg,
                                              bf16* As, bf16* Bs,
                                              floatx4 acc[4][4]) {
  int tid = threadIdx.x;
  int w = tid >> 6, l = tid & 63, g = l >> 4, ln = l & 15;
  int wr = (w >> 1) << 6, wc = (w & 1) << 6;
  int lrow = w * 16 + (l >> 2);
  int lkc = (l & 3) * 8;
  for (int k0 = 0; k0 < 1024; k0 += 32) {
    __syncthreads();
    gload_lds16(Ag + (size_t)lrow * 1024 + k0 + lkc, As + w * 512);
    gload_lds16(Ag + (size_t)(lrow + 64) * 1024 + k0 + lkc, As + 2048 + w * 512);
    gload_lds16(Bg + (size_t)lrow * 1024 + k0 + lkc, Bs + w * 512);
    gload_lds16(Bg + (size_t)(lrow + 64) * 1024 + k0 + lkc, Bs + 2048 + w * 512);
    asm volatile("s_waitcnt vmcnt(0)" ::: "memory");
    __syncthreads();
    bf16x8 af[4], bfv[4];
#pragma unroll
    for (int t = 0; t < 4; t++) {
      af[t] = *(const bf16x8*)&As[(wr + t * 16 + ln) * 32 + g * 8];
      bfv[t] = *(const bf16x8*)&Bs[(wc + t * 16 + ln) * 32 + g * 8];
    }
#pragma unroll
    for (int i = 0; i < 4; i++)
#pragma unroll
      for (int j = 0; j < 4; j++)
        acc[i][j] = MFMA16(af[i], bfv[j], acc[i][j]);
  }
}

// ---------------------------------------------------------------- QKV projection
// Round-6: z==2 (V) writes DIRECTLY in transposed layout Vt[bh][d][n] from
// the register tile (scatter completes lines in L2; HBM traffic unchanged),
// eliminating the separate vtrans kernel + its 32 MB round trip.
__global__ __launch_bounds__(256) void qkv_proj(
    const bf16* __restrict__ xb, const bf16* __restrict__ wqkv,
    bf16* __restrict__ Qo, bf16* __restrict__ Ko, bf16* __restrict__ Vto) {
  __shared__ bf16 As[4096], Bs[4096];
  const floatx4 z4 = {0.f, 0.f, 0.f, 0.f};
  floatx4 acc[4][4];
#pragma unroll
  for (int i = 0; i < 4; i++)
#pragma unroll
    for (int j = 0; j < 4; j++) acc[i][j] = z4;
  int z = blockIdx.z;
  const bf16* Ag = xb + (size_t)blockIdx.x * 128 * 1024;
  const bf16* Bg = wqkv + (size_t)z * 1048576 + (size_t)blockIdx.y * 128 * 1024;
  gemm_mainloop(Ag, Bg, As, Bs, acc);
  int tid = threadIdx.x, w = tid >> 6, l = tid & 63, g = l >> 4, ln = l & 15;
  int mbase = blockIdx.x * 128 + ((w >> 1) << 6);
  int ibase = blockIdx.y * 128 + ((w & 1) << 6);  // 64-aligned
  if (z == 2) {
    // Vt[bh][di][n]: bh = b*16 + (ibase>>6); di = j*16+ln; n = m&1023
    int hbase = ibase >> 6;
#pragma unroll
    for (int i = 0; i < 4; i++)
#pragma unroll
      for (int j = 0; j < 4; j++)
#pragma unroll
        for (int r = 0; r < 4; r++) {
          int m = mbase + i * 16 + g * 4 + r;
          int b = m >> 10, n = m & 1023;
          int di = j * 16 + ln;
          Vto[((size_t)((b * 16 + hbase) * 64 + di) << 10) + n] =
              (bf16)acc[i][j][r];
        }
  } else {
    bf16* dst = z == 0 ? Qo : Ko;
#pragma unroll
    for (int i = 0; i < 4; i++)
#pragma unroll
      for (int j = 0; j < 4; j++)
#pragma unroll
        for (int r = 0; r < 4; r++) {
          int m = mbase + i * 16 + g * 4 + r;
          int col = ibase + j * 16 + ln;
          int b = m >> 10, n = m & 1023, h = col >> 6, di = col & 63;
          dst[((size_t)((b * 16 + h) * 1024 + n) << 6) + di] = (bf16)acc[i][j][r];
        }
  }
}

// ---------------------------------------------------------------- flash attention
// flash is bias-HBM-bound (268 MB fp32 bias stream ~= 43 us floor); K/V
// staging via global_load_lds with both-sides XOR swizzle; 40 KB LDS,
// 4 blocks/CU; XCD-chunked block swizzle.
__global__ __launch_bounds__(256, 4) void flash_kernel(
    const bf16* __restrict__ Q, const bf16* __restrict__ Kg,
    const bf16* __restrict__ Vt, const float* __restrict__ bias,
    bf16* __restrict__ Ao) {
  __shared__ __align__(16) bf16 Klds[2][4096];  // [buf] 64key x 64d, swizzled
  __shared__ __align__(16) bf16 Vlds[2][4096];  // [buf] 64d x 64key, swizzled
  __shared__ __align__(16) bf16 Plds[4 * 16 * 64];  // per-wave P, XOR-swizzled
  int tid = threadIdx.x;
  int w = tid >> 6, l = tid & 63, g = l >> 4, ln = l & 15;
  // XCD swizzle: nwg=1024=8*128, bijective chunked transform
  int flat = blockIdx.y * 16 + blockIdx.x;
  int lg = (flat & 7) * 128 + (flat >> 3);
  int qt = lg & 15;   // 0..15
  int bh = lg >> 4;   // 0..63
  size_t bhN = (size_t)bh * 1024;

  // staging: per thread two 16B chunks each of K and V^T tile (8KB each).
  // dest byte D in tile is linear; source global byte = D ^ (((D>>7)&7)<<4).
  int D0 = w * 2048 + l * 16;
  int D1 = D0 + 1024;
  int S0 = D0 ^ (((D0 >> 7) & 7) << 4);
  int S1 = D1 ^ (((D1 >> 7) & 7) << 4);
  const bf16* Ks0 = Kg + bhN * 64 + (S0 >> 1);
  const bf16* Ks1 = Kg + bhN * 64 + (S1 >> 1);
  const bf16* Vs0 = Vt + bhN * 64 + (size_t)(S0 >> 7) * 1024 + ((S0 & 127) >> 1);
  const bf16* Vs1 = Vt + bhN * 64 + (size_t)(S1 >> 7) * 1024 + ((S1 & 127) >> 1);

  // issue kb=0 stage
  gload_lds16(Ks0, &Klds[0][w * 1024]);
  gload_lds16(Ks1, &Klds[0][w * 1024 + 512]);
  gload_lds16(Vs0, &Vlds[0][w * 1024]);
  gload_lds16(Vs1, &Vlds[0][w * 1024 + 512]);

  // Q fragments (A-layout: m=lane&15, k=(lane>>4)*8+j)
  const bf16* qptr = Q + (bhN + qt * 64 + w * 16 + ln) * 64;
  bf16x8 qf0 = *(const bf16x8*)(qptr + g * 8);
  bf16x8 qf1 = *(const bf16x8*)(qptr + 32 + g * 8);

  // bias base; rows (w*16+g*4+r), cols (t*16+ln), loaded per-iteration
  const float* bbase = bias + ((bhN + qt * 64 + w * 16 + g * 4) << 10) + ln;

  const floatx4 z4 = {0.f, 0.f, 0.f, 0.f};
  floatx4 o[4];
  float m_i[4], l_i[4];
#pragma unroll
  for (int i = 0; i < 4; i++) { o[i] = z4; m_i[i] = -1e30f; l_i[i] = 0.f; }

  // swizzled fragment read byte-offsets within a row (row stride 128B)
  int sx = (ln & 7) << 4;
  int rc0 = (g * 16) ^ sx;        // k-cols 0..31 (elements g*8..)
  int rc1 = (64 + g * 16) ^ sx;   // k-cols 32..63

  asm volatile("s_waitcnt vmcnt(0)" ::: "memory");
  __syncthreads();

  char* pw = (char*)(Plds + w * 16 * 64);  // per-wave 16x64, swizzled bytes

#pragma unroll 2
  for (int kb = 0; kb < 16; kb++) {
    int cur = kb & 1, nxt = cur ^ 1;
    // ---- bias loads for THIS iteration, issued first (so waiting on bc
    // leaves the 4 K/V prefetch loads in flight)
    float bc[4][4];
    {
      const float* bp = bbase + kb * 64;
#pragma unroll
      for (int t = 0; t < 4; t++)
#pragma unroll
        for (int r = 0; r < 4; r++) bc[t][r] = bp[(size_t)r * 1024 + t * 16];
    }
    // ---- issue stage of kb+1 into buf nxt (in flight across the whole
    // iteration's compute)
    if (kb < 15) {
      gload_lds16(Ks0 + (kb + 1) * 4096, &Klds[nxt][w * 1024]);
      gload_lds16(Ks1 + (kb + 1) * 4096, &Klds[nxt][w * 1024 + 512]);
      gload_lds16(Vs0 + (kb + 1) * 64, &Vlds[nxt][w * 1024]);
      gload_lds16(Vs1 + (kb + 1) * 64, &Vlds[nxt][w * 1024 + 512]);
    }

    // ---- S = Q K^T from buffer cur
    const char* Kc = (const char*)&Klds[cur][0];
    floatx4 s[4];
#pragma unroll
    for (int t = 0; t < 4; t++) {
      s[t] = z4;
      bf16x8 kf0 = *(const bf16x8*)(Kc + (t * 16 + ln) * 128 + rc0);
      bf16x8 kf1 = *(const bf16x8*)(Kc + (t * 16 + ln) * 128 + rc1);
      s[t] = MFMA16(qf0, kf0, s[t]);
      s[t] = MFMA16(qf1, kf1, s[t]);
    }
#pragma unroll
    for (int t = 0; t < 4; t++)
#pragma unroll
      for (int r = 0; r < 4; r++)
        s[t][r] = fmaf(s[t][r], 0.125f, bc[t][r]);

    // ---- online softmax (rows live across 16 lanes of group g)
    float cmax[4], rs[4], alpha[4];
#pragma unroll
    for (int r = 0; r < 4; r++)
      cmax[r] = fmaxf(fmaxf(s[0][r], s[1][r]), fmaxf(s[2][r], s[3][r]));
#pragma unroll
    for (int mk = 1; mk < 16; mk <<= 1)
#pragma unroll
      for (int r = 0; r < 4; r++)
        cmax[r] = fmaxf(cmax[r], __shfl_xor(cmax[r], mk, 64));
#pragma unroll
    for (int r = 0; r < 4; r++) {
      float mn = fmaxf(m_i[r], cmax[r]);
      alpha[r] = __expf(m_i[r] - mn);
      m_i[r] = mn;
      rs[r] = 0.f;
    }
#pragma unroll
    for (int t = 0; t < 4; t++)
#pragma unroll
      for (int r = 0; r < 4; r++) {
        float p = __expf(s[t][r] - m_i[r]);
        s[t][r] = p;
        rs[r] += p;
      }
#pragma unroll
    for (int mk = 1; mk < 16; mk <<= 1)
#pragma unroll
      for (int r = 0; r < 4; r++) rs[r] += __shfl_xor(rs[r], mk, 64);
#pragma unroll
    for (int r = 0; r < 4; r++) l_i[r] = l_i[r] * alpha[r] + rs[r];
#pragma unroll
    for (int dt = 0; dt < 4; dt++)
#pragma unroll
      for (int r = 0; r < 4; r++) o[dt][r] *= alpha[r];

    // ---- P: C-layout -> swizzled LDS -> A-layout frags (wave-private)
#pragma unroll
    for (int t = 0; t < 4; t++)
#pragma unroll
      for (int r = 0; r < 4; r++) {
        int prow = g * 4 + r;
        *(bf16*)(pw + prow * 128 + (((t * 16 + ln) * 2) ^ ((prow & 7) << 4))) =
            (bf16)s[t][r];
      }
    asm volatile("s_waitcnt lgkmcnt(0)" ::: "memory");

    bf16x8 pf0 = *(const bf16x8*)(pw + ln * 128 + ((g * 16) ^ sx));
    bf16x8 pf1 = *(const bf16x8*)(pw + ln * 128 + ((64 + g * 16) ^ sx));
    const char* Vc = (const char*)&Vlds[cur][0];
#pragma unroll
    for (int dt = 0; dt < 4; dt++) {
      bf16x8 vf0 = *(const bf16x8*)(Vc + (dt * 16 + ln) * 128 + rc0);
      bf16x8 vf1 = *(const bf16x8*)(Vc + (dt * 16 + ln) * 128 + rc1);
      o[dt] = MFMA16(pf0, vf0, o[dt]);
      o[dt] = MFMA16(pf1, vf1, o[dt]);
    }

    // ---- retire prefetch, flip buffers
    if (kb < 15) {
      asm volatile("s_waitcnt vmcnt(0)" ::: "memory");
      __syncthreads();
    }
  }

  // epilogue: O /= l, write attn_out [B*N, 1024] bf16 at col h*64+d
  int b = bh >> 4, h = bh & 15;
#pragma unroll
  for (int r = 0; r < 4; r++) {
    float inv = 1.f / l_i[r];
    int row = b * 1024 + qt * 64 + w * 16 + g * 4 + r;
    bf16* op = Ao + (size_t)row * 1024 + h * 64 + ln;
#pragma unroll
    for (int dt = 0; dt < 4; dt++) op[dt * 16] = (bf16)(o[dt][r] * inv);
  }
}

// ---------------------------------------------------------------- output projection
__global__ __launch_bounds__(256) void out_proj(const bf16* __restrict__ Ab,
                                                const bf16* __restrict__ wob,
                                                float* __restrict__ C) {
  __shared__ bf16 As[4096], Bs[2048];
  const floatx4 z4 = {0.f, 0.f, 0.f, 0.f};
  floatx4 acc[4][2];
#pragma unroll
  for (int i = 0; i < 4; i++)
#pragma unroll
    for (int j = 0; j < 2; j++) acc[i][j] = z4;
  const bf16* Ag = Ab + (size_t)blockIdx.x * 128 * 1024;
  const bf16* Bg = wob + (size_t)blockIdx.y * 64 * 1024;
  int tid = threadIdx.x;
  int w = tid >> 6, l = tid & 63, g = l >> 4, ln = l & 15;
  int wr = (w >> 1) << 6, wc = (w & 1) << 5;
  int lrow = w * 16 + (l >> 2);
  int lkc = (l & 3) * 8;
  for (int k0 = 0; k0 < 1024; k0 += 32) {
    __syncthreads();
    gload_lds16(Ag + (size_t)lrow * 1024 + k0 + lkc, As + w * 512);
    gload_lds16(Ag + (size_t)(lrow + 64) * 1024 + k0 + lkc, As + 2048 + w * 512);
    gload_lds16(Bg + (size_t)lrow * 1024 + k0 + lkc, Bs + w * 512);
    asm volatile("s_waitcnt vmcnt(0)" ::: "memory");
    __syncthreads();
    bf16x8 af[4], bfv[2];
#pragma unroll
    for (int t = 0; t < 4; t++)
      af[t] = *(const bf16x8*)&As[(wr + t * 16 + ln) * 32 + g * 8];
#pragma unroll
    for (int t = 0; t < 2; t++)
      bfv[t] = *(const bf16x8*)&Bs[(wc + t * 16 + ln) * 32 + g * 8];
#pragma unroll
    for (int i = 0; i < 4; i++)
#pragma unroll
      for (int j = 0; j < 2; j++)
        acc[i][j] = MFMA16(af[i], bfv[j], acc[i][j]);
  }
  int mbase = blockIdx.x * 128 + wr;
  int cbase = blockIdx.y * 64 + wc;
#pragma unroll
  for (int i = 0; i < 4; i++)
#pragma unroll
    for (int j = 0; j < 2; j++)
#pragma unroll
      for (int r = 0; r < 4; r++)
        C[(size_t)(mbase + i * 16 + g * 4 + r) * 1024 + cbase + j * 16 + ln] =
            acc[i][j][r];
}

// ---------------------------------------------------------------- launch
extern "C" void kernel_launch(void* const* d_in, const int* in_sizes, int n_in,
                              void* d_out, int out_size, void* d_ws, size_t ws_size,
                              hipStream_t stream) {
  const float* x = (const float*)d_in[0];
  const float* bias = (const float*)d_in[1];
  const float* Wq = (const float*)d_in[2];
  const float* Wk = (const float*)d_in[3];
  const float* Wv = (const float*)d_in[4];
  const float* Wo = (const float*)d_in[5];
  float* out = (float*)d_out;

  bf16* xb = (bf16*)d_ws;            // 4194304
  bf16* wqkv = xb + 4194304;         // 3*1048576 (Wq,Wk,Wv)
  bf16* wob = wqkv + 3 * 1048576;    // 1048576
  bf16* Qb = wob + 1048576;          // 4194304  [B,H,N,64]
  bf16* Kb = Qb + 4194304;           // 4194304
  bf16* Vtb = Kb + 4194304;          // 4194304  [B,H,64,1024] = V^T per head
  bf16* Ao = Vtb + 4194304;          // 4194304  [B*N, 1024]

  cvt_kernel<<<8192, 256, 0, stream>>>(x, Wq, Wk, Wv, Wo, xb);
  qkv_proj<<<dim3(32, 8, 3), 256, 0, stream>>>(xb, wqkv, Qb, Kb, Vtb);
  flash_kernel<<<dim3(16, 64), 256, 0, stream>>>(Qb, Kb, Vtb, bias, Ao);
  out_proj<<<dim3(32, 16), 256, 0, stream>>>(Ao, wob, out);
}

// Round 4
// 457.981 us; speedup vs baseline: 1.0456x; 1.0456x over previous
//
#include <hip/hip_runtime.h>
#include <hip/hip_bf16.h>
#include <math.h>

// AttentionWithBias: B=4, N=1024, d=1024, H=16, hd=64
// bf16 MFMA (16x16x32), fp32 accumulate, fp32 softmax+bias.

typedef __bf16 bf16;
typedef bf16 bf16x8 __attribute__((ext_vector_type(8)));
typedef bf16 bf16x4 __attribute__((ext_vector_type(4)));
typedef float floatx4 __attribute__((ext_vector_type(4)));

#define MFMA16(a, b, c) __builtin_amdgcn_mfma_f32_16x16x32_bf16((a), (b), (c), 0, 0, 0)

__device__ __forceinline__ void gload_lds16(const bf16* g, bf16* l) {
  __builtin_amdgcn_global_load_lds(
      (const __attribute__((address_space(1))) unsigned int*)g,
      (__attribute__((address_space(3))) unsigned int*)l, 16, 0, 0);
}

// ---------------------------------------------------------------- convert
__global__ __launch_bounds__(256) void cvt_kernel(
    const float* __restrict__ x, const float* __restrict__ wq,
    const float* __restrict__ wk, const float* __restrict__ wv,
    const float* __restrict__ wo, bf16* __restrict__ dst) {
  long e = ((long)blockIdx.x * 256 + threadIdx.x) * 4;
  const float* src;
  if (e < 4194304) {
    src = x + e;
  } else {
    long r = (e - 4194304) >> 20;
    long off = (e - 4194304) & 1048575;
    src = (r == 0 ? wq : r == 1 ? wk : r == 2 ? wv : wo) + off;
  }
  float4 v = *reinterpret_cast<const float4*>(src);
  bf16x4 o = { (bf16)v.x, (bf16)v.y, (bf16)v.z, (bf16)v.w };
  *reinterpret_cast<bf16x4*>(dst + e) = o;
}

// ---------------------------------------------------------------- GEMM core
__device__ __forceinline__ void gemm_mainloop(const bf16* __restrict__ Ag,
                                              const bf16* __restrict__ Bg,
                                              bf16* As, bf16* Bs,
                                              floatx4 acc[4][4]) {
  int tid = threadIdx.x;
  int w = tid >> 6, l = tid & 63, g = l >> 4, ln = l & 15;
  int wr = (w >> 1) << 6, wc = (w & 1) << 6;
  int lrow = w * 16 + (l >> 2);
  int lkc = (l & 3) * 8;
  for (int k0 = 0; k0 < 1024; k0 += 32) {
    __syncthreads();
    gload_lds16(Ag + (size_t)lrow * 1024 + k0 + lkc, As + w * 512);
    gload_lds16(Ag + (size_t)(lrow + 64) * 1024 + k0 + lkc, As + 2048 + w * 512);
    gload_lds16(Bg + (size_t)lrow * 1024 + k0 + lkc, Bs + w * 512);
    gload_lds16(Bg + (size_t)(lrow + 64) * 1024 + k0 + lkc, Bs + 2048 + w * 512);
    asm volatile("s_waitcnt vmcnt(0)" ::: "memory");
    __syncthreads();
    bf16x8 af[4], bfv[4];
#pragma unroll
    for (int t = 0; t < 4; t++) {
      af[t] = *(const bf16x8*)&As[(wr + t * 16 + ln) * 32 + g * 8];
      bfv[t] = *(const bf16x8*)&Bs[(wc + t * 16 + ln) * 32 + g * 8];
    }
#pragma unroll
    for (int i = 0; i < 4; i++)
#pragma unroll
      for (int j = 0; j < 4; j++)
        acc[i][j] = MFMA16(af[i], bfv[j], acc[i][j]);
  }
}

// ---------------------------------------------------------------- QKV projection
// Round-7: z==2 (V) writes Vt[bh][d][n] via a PER-WAVE LDS transpose of its
// 64x64 register tile (reusing the dead As/Bs staging LDS), emitting 16B
// stores 64B-contiguous across lane groups — instead of R6's 2B scatter
// (64 lines x 2B per instr, 8x the L2 write transactions).
__global__ __launch_bounds__(256) void qkv_proj(
    const bf16* __restrict__ xb, const bf16* __restrict__ wqkv,
    bf16* __restrict__ Qo, bf16* __restrict__ Ko, bf16* __restrict__ Vto) {
  __shared__ bf16 As[4096], Bs[4096];
  const floatx4 z4 = {0.f, 0.f, 0.f, 0.f};
  floatx4 acc[4][4];
#pragma unroll
  for (int i = 0; i < 4; i++)
#pragma unroll
    for (int j = 0; j < 4; j++) acc[i][j] = z4;
  int z = blockIdx.z;
  const bf16* Ag = xb + (size_t)blockIdx.x * 128 * 1024;
  const bf16* Bg = wqkv + (size_t)z * 1048576 + (size_t)blockIdx.y * 128 * 1024;
  gemm_mainloop(Ag, Bg, As, Bs, acc);
  int tid = threadIdx.x, w = tid >> 6, l = tid & 63, g = l >> 4, ln = l & 15;
  int mbase = blockIdx.x * 128 + ((w >> 1) << 6);
  int ibase = blockIdx.y * 128 + ((w & 1) << 6);  // 64-aligned
  if (z == 2) {
    // wave-private scratch [32][64] in the (now dead) staging LDS
    __syncthreads();  // all waves done reading As/Bs in mainloop
    bf16* scratch = (w < 2 ? As : Bs) + (w & 1) * 2048;
    int hbase = (blockIdx.y << 1) | (w & 1);
    int b = mbase >> 10;
    size_t vbase = ((size_t)((b * 16 + hbase) * 64) << 10);
    int n00 = mbase & 1023;  // 64-aligned, chunk stays within one b
#pragma unroll
    for (int c = 0; c < 2; c++) {
      // write chunk c (m-rows [c*32, c*32+32)) with row-XOR bank swizzle
#pragma unroll
      for (int ih = 0; ih < 2; ih++) {
        int i = c * 2 + ih;
#pragma unroll
        for (int j = 0; j < 4; j++)
#pragma unroll
          for (int r = 0; r < 4; r++) {
            int row = ih * 16 + g * 4 + r;
            int colv = (j * 16 + ln) ^ (((row >> 2) & 3) << 4);
            scratch[row * 64 + colv] = (bf16)acc[i][j][r];
          }
      }
      __syncthreads();
      // read transposed: lane owns di = dq*16 + (l>>2), n-group (l&3)*8
#pragma unroll
      for (int dq = 0; dq < 4; dq++) {
        int di = dq * 16 + (l >> 2);
        int nl = (l & 3) * 8;
        bf16x8 v;
#pragma unroll
        for (int k = 0; k < 8; k++) {
          int row = nl + k;
          v[k] = scratch[row * 64 + (di ^ (((row >> 2) & 3) << 4))];
        }
        *(bf16x8*)(Vto + vbase + ((size_t)di << 10) + n00 + c * 32 + nl) = v;
      }
      __syncthreads();
    }
  } else {
    bf16* dst = z == 0 ? Qo : Ko;
#pragma unroll
    for (int i = 0; i < 4; i++)
#pragma unroll
      for (int j = 0; j < 4; j++)
#pragma unroll
        for (int r = 0; r < 4; r++) {
          int m = mbase + i * 16 + g * 4 + r;
          int col = ibase + j * 16 + ln;
          int b = m >> 10, n = m & 1023, h = col >> 6, di = col & 63;
          dst[((size_t)((b * 16 + h) * 1024 + n) << 6) + di] = (bf16)acc[i][j][r];
        }
  }
}

// ---------------------------------------------------------------- flash attention
// flash is bias-HBM-bound (268 MB fp32 bias stream ~= 43 us floor); K/V
// staging via global_load_lds with both-sides XOR swizzle; 40 KB LDS,
// 4 blocks/CU; XCD-chunked block swizzle.
__global__ __launch_bounds__(256, 4) void flash_kernel(
    const bf16* __restrict__ Q, const bf16* __restrict__ Kg,
    const bf16* __restrict__ Vt, const float* __restrict__ bias,
    bf16* __restrict__ Ao) {
  __shared__ __align__(16) bf16 Klds[2][4096];  // [buf] 64key x 64d, swizzled
  __shared__ __align__(16) bf16 Vlds[2][4096];  // [buf] 64d x 64key, swizzled
  __shared__ __align__(16) bf16 Plds[4 * 16 * 64];  // per-wave P, XOR-swizzled
  int tid = threadIdx.x;
  int w = tid >> 6, l = tid & 63, g = l >> 4, ln = l & 15;
  // XCD swizzle: nwg=1024=8*128, bijective chunked transform
  int flat = blockIdx.y * 16 + blockIdx.x;
  int lg = (flat & 7) * 128 + (flat >> 3);
  int qt = lg & 15;   // 0..15
  int bh = lg >> 4;   // 0..63
  size_t bhN = (size_t)bh * 1024;

  // staging: per thread two 16B chunks each of K and V^T tile (8KB each).
  // dest byte D in tile is linear; source global byte = D ^ (((D>>7)&7)<<4).
  int D0 = w * 2048 + l * 16;
  int D1 = D0 + 1024;
  int S0 = D0 ^ (((D0 >> 7) & 7) << 4);
  int S1 = D1 ^ (((D1 >> 7) & 7) << 4);
  const bf16* Ks0 = Kg + bhN * 64 + (S0 >> 1);
  const bf16* Ks1 = Kg + bhN * 64 + (S1 >> 1);
  const bf16* Vs0 = Vt + bhN * 64 + (size_t)(S0 >> 7) * 1024 + ((S0 & 127) >> 1);
  const bf16* Vs1 = Vt + bhN * 64 + (size_t)(S1 >> 7) * 1024 + ((S1 & 127) >> 1);

  // issue kb=0 stage
  gload_lds16(Ks0, &Klds[0][w * 1024]);
  gload_lds16(Ks1, &Klds[0][w * 1024 + 512]);
  gload_lds16(Vs0, &Vlds[0][w * 1024]);
  gload_lds16(Vs1, &Vlds[0][w * 1024 + 512]);

  // Q fragments (A-layout: m=lane&15, k=(lane>>4)*8+j)
  const bf16* qptr = Q + (bhN + qt * 64 + w * 16 + ln) * 64;
  bf16x8 qf0 = *(const bf16x8*)(qptr + g * 8);
  bf16x8 qf1 = *(const bf16x8*)(qptr + 32 + g * 8);

  // bias base; rows (w*16+g*4+r), cols (t*16+ln), loaded per-iteration
  const float* bbase = bias + ((bhN + qt * 64 + w * 16 + g * 4) << 10) + ln;

  const floatx4 z4 = {0.f, 0.f, 0.f, 0.f};
  floatx4 o[4];
  float m_i[4], l_i[4];
#pragma unroll
  for (int i = 0; i < 4; i++) { o[i] = z4; m_i[i] = -1e30f; l_i[i] = 0.f; }

  // swizzled fragment read byte-offsets within a row (row stride 128B)
  int sx = (ln & 7) << 4;
  int rc0 = (g * 16) ^ sx;        // k-cols 0..31 (elements g*8..)
  int rc1 = (64 + g * 16) ^ sx;   // k-cols 32..63

  asm volatile("s_waitcnt vmcnt(0)" ::: "memory");
  __syncthreads();

  char* pw = (char*)(Plds + w * 16 * 64);  // per-wave 16x64, swizzled bytes

#pragma unroll 2
  for (int kb = 0; kb < 16; kb++) {
    int cur = kb & 1, nxt = cur ^ 1;
    // ---- bias loads for THIS iteration, issued first (so waiting on bc
    // leaves the 4 K/V prefetch loads in flight)
    float bc[4][4];
    {
      const float* bp = bbase + kb * 64;
#pragma unroll
      for (int t = 0; t < 4; t++)
#pragma unroll
        for (int r = 0; r < 4; r++) bc[t][r] = bp[(size_t)r * 1024 + t * 16];
    }
    // ---- issue stage of kb+1 into buf nxt (in flight across the whole
    // iteration's compute)
    if (kb < 15) {
      gload_lds16(Ks0 + (kb + 1) * 4096, &Klds[nxt][w * 1024]);
      gload_lds16(Ks1 + (kb + 1) * 4096, &Klds[nxt][w * 1024 + 512]);
      gload_lds16(Vs0 + (kb + 1) * 64, &Vlds[nxt][w * 1024]);
      gload_lds16(Vs1 + (kb + 1) * 64, &Vlds[nxt][w * 1024 + 512]);
    }

    // ---- S = Q K^T from buffer cur
    const char* Kc = (const char*)&Klds[cur][0];
    floatx4 s[4];
#pragma unroll
    for (int t = 0; t < 4; t++) {
      s[t] = z4;
      bf16x8 kf0 = *(const bf16x8*)(Kc + (t * 16 + ln) * 128 + rc0);
      bf16x8 kf1 = *(const bf16x8*)(Kc + (t * 16 + ln) * 128 + rc1);
      s[t] = MFMA16(qf0, kf0, s[t]);
      s[t] = MFMA16(qf1, kf1, s[t]);
    }
#pragma unroll
    for (int t = 0; t < 4; t++)
#pragma unroll
      for (int r = 0; r < 4; r++)
        s[t][r] = fmaf(s[t][r], 0.125f, bc[t][r]);

    // ---- online softmax (rows live across 16 lanes of group g)
    float cmax[4], rs[4], alpha[4];
#pragma unroll
    for (int r = 0; r < 4; r++)
      cmax[r] = fmaxf(fmaxf(s[0][r], s[1][r]), fmaxf(s[2][r], s[3][r]));
#pragma unroll
    for (int mk = 1; mk < 16; mk <<= 1)
#pragma unroll
      for (int r = 0; r < 4; r++)
        cmax[r] = fmaxf(cmax[r], __shfl_xor(cmax[r], mk, 64));
#pragma unroll
    for (int r = 0; r < 4; r++) {
      float mn = fmaxf(m_i[r], cmax[r]);
      alpha[r] = __expf(m_i[r] - mn);
      m_i[r] = mn;
      rs[r] = 0.f;
    }
#pragma unroll
    for (int t = 0; t < 4; t++)
#pragma unroll
      for (int r = 0; r < 4; r++) {
        float p = __expf(s[t][r] - m_i[r]);
        s[t][r] = p;
        rs[r] += p;
      }
#pragma unroll
    for (int mk = 1; mk < 16; mk <<= 1)
#pragma unroll
      for (int r = 0; r < 4; r++) rs[r] += __shfl_xor(rs[r], mk, 64);
#pragma unroll
    for (int r = 0; r < 4; r++) l_i[r] = l_i[r] * alpha[r] + rs[r];
#pragma unroll
    for (int dt = 0; dt < 4; dt++)
#pragma unroll
      for (int r = 0; r < 4; r++) o[dt][r] *= alpha[r];

    // ---- P: C-layout -> swizzled LDS -> A-layout frags (wave-private)
#pragma unroll
    for (int t = 0; t < 4; t++)
#pragma unroll
      for (int r = 0; r < 4; r++) {
        int prow = g * 4 + r;
        *(bf16*)(pw + prow * 128 + (((t * 16 + ln) * 2) ^ ((prow & 7) << 4))) =
            (bf16)s[t][r];
      }
    asm volatile("s_waitcnt lgkmcnt(0)" ::: "memory");

    bf16x8 pf0 = *(const bf16x8*)(pw + ln * 128 + ((g * 16) ^ sx));
    bf16x8 pf1 = *(const bf16x8*)(pw + ln * 128 + ((64 + g * 16) ^ sx));
    const char* Vc = (const char*)&Vlds[cur][0];
#pragma unroll
    for (int dt = 0; dt < 4; dt++) {
      bf16x8 vf0 = *(const bf16x8*)(Vc + (dt * 16 + ln) * 128 + rc0);
      bf16x8 vf1 = *(const bf16x8*)(Vc + (dt * 16 + ln) * 128 + rc1);
      o[dt] = MFMA16(pf0, vf0, o[dt]);
      o[dt] = MFMA16(pf1, vf1, o[dt]);
    }

    // ---- retire prefetch, flip buffers
    if (kb < 15) {
      asm volatile("s_waitcnt vmcnt(0)" ::: "memory");
      __syncthreads();
    }
  }

  // epilogue: O /= l, write attn_out [B*N, 1024] bf16 at col h*64+d
  int b = bh >> 4, h = bh & 15;
#pragma unroll
  for (int r = 0; r < 4; r++) {
    float inv = 1.f / l_i[r];
    int row = b * 1024 + qt * 64 + w * 16 + g * 4 + r;
    bf16* op = Ao + (size_t)row * 1024 + h * 64 + ln;
#pragma unroll
    for (int dt = 0; dt < 4; dt++) op[dt * 16] = (bf16)(o[dt][r] * inv);
  }
}

// ---------------------------------------------------------------- output projection
__global__ __launch_bounds__(256) void out_proj(const bf16* __restrict__ Ab,
                                                const bf16* __restrict__ wob,
                                                float* __restrict__ C) {
  __shared__ bf16 As[4096], Bs[2048];
  const floatx4 z4 = {0.f, 0.f, 0.f, 0.f};
  floatx4 acc[4][2];
#pragma unroll
  for (int i = 0; i < 4; i++)
#pragma unroll
    for (int j = 0; j < 2; j++) acc[i][j] = z4;
  const bf16* Ag = Ab + (size_t)blockIdx.x * 128 * 1024;
  const bf16* Bg = wob + (size_t)blockIdx.y * 64 * 1024;
  int tid = threadIdx.x;
  int w = tid >> 6, l = tid & 63, g = l >> 4, ln = l & 15;
  int wr = (w >> 1) << 6, wc = (w & 1) << 5;
  int lrow = w * 16 + (l >> 2);
  int lkc = (l & 3) * 8;
  for (int k0 = 0; k0 < 1024; k0 += 32) {
    __syncthreads();
    gload_lds16(Ag + (size_t)lrow * 1024 + k0 + lkc, As + w * 512);
    gload_lds16(Ag + (size_t)(lrow + 64) * 1024 + k0 + lkc, As + 2048 + w * 512);
    gload_lds16(Bg + (size_t)lrow * 1024 + k0 + lkc, Bs + w * 512);
    asm volatile("s_waitcnt vmcnt(0)" ::: "memory");
    __syncthreads();
    bf16x8 af[4], bfv[2];
#pragma unroll
    for (int t = 0; t < 4; t++)
      af[t] = *(const bf16x8*)&As[(wr + t * 16 + ln) * 32 + g * 8];
#pragma unroll
    for (int t = 0; t < 2; t++)
      bfv[t] = *(const bf16x8*)&Bs[(wc + t * 16 + ln) * 32 + g * 8];
#pragma unroll
    for (int i = 0; i < 4; i++)
#pragma unroll
      for (int j = 0; j < 2; j++)
        acc[i][j] = MFMA16(af[i], bfv[j], acc[i][j]);
  }
  int mbase = blockIdx.x * 128 + wr;
  int cbase = blockIdx.y * 64 + wc;
#pragma unroll
  for (int i = 0; i < 4; i++)
#pragma unroll
    for (int j = 0; j < 2; j++)
#pragma unroll
      for (int r = 0; r < 4; r++)
        C[(size_t)(mbase + i * 16 + g * 4 + r) * 1024 + cbase + j * 16 + ln] =
            acc[i][j][r];
}

// ---------------------------------------------------------------- launch
extern "C" void kernel_launch(void* const* d_in, const int* in_sizes, int n_in,
                              void* d_out, int out_size, void* d_ws, size_t ws_size,
                              hipStream_t stream) {
  const float* x = (const float*)d_in[0];
  const float* bias = (const float*)d_in[1];
  const float* Wq = (const float*)d_in[2];
  const float* Wk = (const float*)d_in[3];
  const float* Wv = (const float*)d_in[4];
  const float* Wo = (const float*)d_in[5];
  float* out = (float*)d_out;

  bf16* xb = (bf16*)d_ws;            // 4194304
  bf16* wqkv = xb + 4194304;         // 3*1048576 (Wq,Wk,Wv)
  bf16* wob = wqkv + 3 * 1048576;    // 1048576
  bf16* Qb = wob + 1048576;          // 4194304  [B,H,N,64]
  bf16* Kb = Qb + 4194304;           // 4194304
  bf16* Vtb = Kb + 4194304;          // 4194304  [B,H,64,1024] = V^T per head
  bf16* Ao = Vtb + 4194304;          // 4194304  [B*N, 1024]

  cvt_kernel<<<8192, 256, 0, stream>>>(x, Wq, Wk, Wv, Wo, xb);
  qkv_proj<<<dim3(32, 8, 3), 256, 0, stream>>>(xb, wqkv, Qb, Kb, Vtb);
  flash_kernel<<<dim3(16, 64), 256, 0, stream>>>(Qb, Kb, Vtb, bias, Ao);
  out_proj<<<dim3(32, 16), 256, 0, stream>>>(Ao, wob, out);
}